// Round 6
// baseline (17.200 us; speedup 1.0000x reference)
//
#include <hip/hip_runtime.h>
#include <math.h>

#define BB   512
#define NBLK 32     // blocks; 8 waves x 2 rows each -> 512 rows
#define TPB  512

// Per-row loss: given lane-held 8 columns d[8] of row j, labels lab[8],
// anchor label myLab. Accumulates loss sum and positive count (lane-uniform
// after butterflies). Fully inlined -> static indexing, no scratch.
__device__ __forceinline__ void row_loss(
    const float (&d)[8], const int (&lab)[8], const int myLab,
    const int j, const int base, float& psum, int& npos)
{
    bool neg[8], pos[8];
    float lmax = -INFINITY, lmin = INFINITY;
    #pragma unroll
    for (int u = 0; u < 8; ++u) {
        neg[u] = (lab[u] != myLab);
        pos[u] = (!neg[u]) && (base + u != j);
        lmin = fminf(lmin, d[u]);
        if (neg[u]) lmax = fmaxf(lmax, d[u]);
    }
    #pragma unroll
    for (int m = 32; m; m >>= 1) {
        lmax = fmaxf(lmax, __shfl_xor(lmax, m));
        lmin = fminf(lmin, __shfl_xor(lmin, m));
    }
    // masked_maximum fallback: no unequal label in row -> row min.
    const float neg_in = (lmax == -INFINITY) ? lmin : lmax;

    // Per positive i: shn = min{d[k] : neg[k] && d[k] > d[i]}, else neg_in.
    #pragma unroll
    for (int u = 0; u < 8; ++u) {
        unsigned long long bal = __ballot(pos[u]);
        npos += __popcll(bal);
        while (bal) {
            const int src = __builtin_ctzll(bal);
            bal &= bal - 1;
            const float dpos = __shfl(d[u], src);
            float c = INFINITY;
            #pragma unroll
            for (int v = 0; v < 8; ++v)
                if (neg[v] && d[v] > dpos) c = fminf(c, d[v]);
            #pragma unroll
            for (int m = 32; m; m >>= 1) c = fminf(c, __shfl_xor(c, m));
            const float shn = (c < INFINITY) ? c : neg_in;
            psum += fmaxf(1.0f + dpos - shn, 0.0f);
        }
    }
}

// Single dispatch. 32 blocks x 8 waves; wave w of block b owns rows
// j0 = 16b + 2w and j0+1. Lane owns 8 contiguous columns. Block reduces its
// 16 rows in LDS, publishes one partial pair at agent scope, arrives on a
// counter; the block whose arrival index == 31 (mod 32) folds 32 partials.
__global__ __launch_bounds__(TPB) void tshl_kernel(
    const float* __restrict__ pdist, const int* __restrict__ target,
    float* __restrict__ part_sum, float* __restrict__ part_cnt,
    unsigned int* __restrict__ counter, float* __restrict__ out)
{
    const int lane = threadIdx.x & 63;
    const int w    = threadIdx.x >> 6;
    const int j0   = (blockIdx.x << 4) + (w << 1);
    const int base = lane << 3;

    // Issue all 6 vector loads up front (ILP; one HBM round-trip).
    const float4 a0 = *(const float4*)(pdist + j0 * BB + base);
    const float4 a1 = *(const float4*)(pdist + j0 * BB + base + 4);
    const float4 b0 = *(const float4*)(pdist + (j0 + 1) * BB + base);
    const float4 b1 = *(const float4*)(pdist + (j0 + 1) * BB + base + 4);
    const int4   t0 = *(const int4*)(target + base);
    const int4   t1 = *(const int4*)(target + base + 4);
    const int myLab0 = target[j0];
    const int myLab1 = target[j0 + 1];

    const int   lab[8] = {t0.x, t0.y, t0.z, t0.w, t1.x, t1.y, t1.z, t1.w};
    const float da[8]  = {a0.x, a0.y, a0.z, a0.w, a1.x, a1.y, a1.z, a1.w};
    const float db[8]  = {b0.x, b0.y, b0.z, b0.w, b1.x, b1.y, b1.z, b1.w};

    float psum = 0.0f;
    int   npos = 0;
    row_loss(da, lab, myLab0, j0,     base, psum, npos);
    row_loss(db, lab, myLab1, j0 + 1, base, psum, npos);

    // Block-level reduce of the 8 wave results (fixed order -> deterministic).
    __shared__ float ssum[8], scnt[8];
    if (lane == 0) { ssum[w] = psum; scnt[w] = (float)npos; }
    __syncthreads();

    unsigned int old = 0;
    if (threadIdx.x == 0) {
        float bs = 0.0f, bc = 0.0f;
        #pragma unroll
        for (int e = 0; e < 8; ++e) { bs += ssum[e]; bc += scnt[e]; }
        __hip_atomic_store(&part_sum[blockIdx.x], bs, __ATOMIC_RELAXED,
                           __HIP_MEMORY_SCOPE_AGENT);
        __hip_atomic_store(&part_cnt[blockIdx.x], bc, __ATOMIC_RELAXED,
                           __HIP_MEMORY_SCOPE_AGENT);
        __threadfence();   // release: partials reach device coherence point
        old = __hip_atomic_fetch_add(counter, 1u, __ATOMIC_RELEASE,
                                     __HIP_MEMORY_SCOPE_AGENT);
    }

    if (w == 0) {
        old = __shfl(old, 0);
        // Exactly one block per launch fires, for ANY persisted counter value.
        if ((old & (NBLK - 1)) == (NBLK - 1)) {
            __threadfence();   // acquire: see all other blocks' partials
            float s = 0.0f, c = 0.0f;
            if (lane < NBLK) {
                s = __hip_atomic_load(&part_sum[lane], __ATOMIC_RELAXED,
                                      __HIP_MEMORY_SCOPE_AGENT);
                c = __hip_atomic_load(&part_cnt[lane], __ATOMIC_RELAXED,
                                      __HIP_MEMORY_SCOPE_AGENT);
            }
            #pragma unroll
            for (int m = 32; m; m >>= 1) {
                s += __shfl_xor(s, m);
                c += __shfl_xor(c, m);
            }
            if (lane == 0) out[0] = s / fmaxf(c, 1.0f);
        }
    }
}

extern "C" void kernel_launch(void* const* d_in, const int* in_sizes, int n_in,
                              void* d_out, int out_size, void* d_ws, size_t ws_size,
                              hipStream_t stream) {
    const float* pdist  = (const float*)d_in[0];
    const int*   target = (const int*)d_in[1];
    float* ws             = (float*)d_ws;
    float* part_sum       = ws;                 // [32]
    float* part_cnt       = ws + NBLK;          // [32]
    unsigned int* counter = (unsigned int*)(ws + 2 * NBLK);
    float* out            = (float*)d_out;

    tshl_kernel<<<NBLK, TPB, 0, stream>>>(pdist, target, part_sum, part_cnt,
                                          counter, out);
}